// Round 7
// baseline (274.406 us; speedup 1.0000x reference)
//
#include <hip/hip_runtime.h>
#include <cstdint>
#include <cstddef>

// Problem constants: B=8, S=2048, H=512, M=4096 -> R = B*S = 16384 rows.
#define H_DIM   512
#define M_DIM   4096

typedef unsigned short u16;
typedef short bf16x8 __attribute__((ext_vector_type(8)));   // 8 bf16 in 4 VGPRs
typedef float f32x4  __attribute__((ext_vector_type(4)));

// fp32 -> bf16 round-to-nearest-even
__device__ __forceinline__ u16 f2b(float f) {
  union { float f; uint32_t u; } v; v.f = f;
  uint32_t u = v.u + (0x7FFFu + ((v.u >> 16) & 1u));
  return (u16)(u >> 16);
}

// pack 8 fp32 (two float4) -> bf16x8
__device__ __forceinline__ bf16x8 cvt8(const float4& lo, const float4& hi) {
  union { u16 u[8]; bf16x8 v; } o;
  o.u[0] = f2b(lo.x); o.u[1] = f2b(lo.y); o.u[2] = f2b(lo.z); o.u[3] = f2b(lo.w);
  o.u[4] = f2b(hi.x); o.u[5] = f2b(hi.y); o.u[6] = f2b(hi.z); o.u[7] = f2b(hi.w);
  return o.v;
}

// ---- both weight casts in one launch: 512 blocks x 256 thr, 2x 65536 f4 -----
__global__ void k_f2bf_ww(const float* __restrict__ wk, const float* __restrict__ wo,
                          u16* __restrict__ owk, u16* __restrict__ owo) {
  int i = blockIdx.x * blockDim.x + threadIdx.x;
  const float* src = (i < 65536) ? wk : wo;
  u16* dst = (i < 65536) ? owk : owo;
  int j = i & 65535;
  float4 v = ((const float4*)src)[j];
  ushort4 o;
  o.x = f2b(v.x); o.y = f2b(v.y); o.z = f2b(v.z); o.w = f2b(v.w);
  ((ushort4*)dst)[j] = o;
}

// ---- compaction: scan usage[4096] -> idx map + meta -------------------------
// meta[0]=count, meta[1]=K_eff=round128(count), meta[2]=K_eff/32, meta[3]=K_eff/128
__global__ void k_compact(const int* __restrict__ usage, int* __restrict__ idx,
                          int* __restrict__ meta) {
  __shared__ int cnt[256];
  int t = threadIdx.x;
  int base = t * 16;
  int c = 0;
  #pragma unroll
  for (int i = 0; i < 16; ++i) c += (usage[base + i] > 0) ? 1 : 0;
  cnt[t] = c;
  __syncthreads();
  for (int d = 1; d < 256; d <<= 1) {           // inclusive Hillis-Steele scan
    int v = (t >= d) ? cnt[t - d] : 0;
    __syncthreads();
    cnt[t] += v;
    __syncthreads();
  }
  int pos = cnt[t] - c;                          // exclusive prefix
  for (int i = 0; i < 16; ++i)
    if (usage[base + i] > 0) idx[pos++] = base + i;
  if (t == 0) {
    int total = cnt[255];
    int keff = ((total + 127) >> 7) << 7;        // 128-granular padding
    meta[0] = total; meta[1] = keff; meta[2] = keff >> 5; meta[3] = keff >> 7;
  }
}

// ---- gather keys: L2-normalized, compacted -> bf16 (keys ONLY) --------------
__global__ void k_gather_keys(const float* __restrict__ keys,
                              const int* __restrict__ idx, const int* __restrict__ meta,
                              u16* __restrict__ okeys) {
  int j    = blockIdx.x * 4 + (threadIdx.x >> 6);
  int lane = threadIdx.x & 63;
  int count = meta[0];
  ushort4* kp = (ushort4*)(okeys + (size_t)j * H_DIM);
  if (j >= count) {                 // wave-uniform
    ushort4 z = {0, 0, 0, 0};
    kp[lane] = z; kp[lane + 64] = z;
    return;
  }
  int src = idx[j];
  const float4* rp = (const float4*)(keys + (size_t)src * H_DIM);
  float4 a = rp[lane];
  float4 b = rp[lane + 64];
  float ss = a.x*a.x + a.y*a.y + a.z*a.z + a.w*a.w
           + b.x*b.x + b.y*b.y + b.z*b.z + b.w*b.w;
  #pragma unroll
  for (int d = 1; d < 64; d <<= 1) ss += __shfl_xor(ss, d, 64);
  float s = rsqrtf(ss + 1e-6f);
  ushort4 oa, ob;
  oa.x = f2b(a.x*s); oa.y = f2b(a.y*s); oa.z = f2b(a.z*s); oa.w = f2b(a.w*s);
  ob.x = f2b(b.x*s); ob.y = f2b(b.y*s); ob.z = f2b(b.z*s); ob.w = f2b(b.w*s);
  kp[lane]      = oa;
  kp[lane + 64] = ob;
}

// ---- reduce partial row sums -> reciprocal (n = meta[1]/64 64-chunks) -------
__global__ void k_reduce_l(const float* __restrict__ lpart, float* __restrict__ linv,
                           const int* __restrict__ meta) {
  int r = blockIdx.x * blockDim.x + threadIdx.x;
  int n = meta[1] >> 6;
  float s = 0.0f;
  for (int i = 0; i < n; ++i) s += lpart[(size_t)r * 64 + i];
  linv[r] = 1.0f / s;
}

// =============================================================================
// MW GEMM (128x128, 256 thr, 4 waves): MWt[h,m] = sum_v Wo[h,v]*mvals[idx[m],v]
// values gather + cast fused into B staging.  Unchanged from R6 (verified).
// =============================================================================
__global__ __launch_bounds__(256, 3)
void k_gemm_mw(const u16* __restrict__ A, const float* __restrict__ Bf,
               const int* __restrict__ idx, const int* __restrict__ meta,
               u16* __restrict__ outh) {
  __shared__ u16 Ah[2][128 * 32];
  __shared__ u16 Bh[2][128 * 32];

  const int tid  = threadIdx.x;
  const int wave = tid >> 6, lane = tid & 63;
  const int wr = (wave >> 1) * 64;
  const int wc = (wave & 1) * 64;

  const int count = meta[0];
  if (blockIdx.x >= (meta[1] >> 7)) return;       // inactive m-block
  const int row0 = blockIdx.y << 7;               // h block
  const int col0 = blockIdx.x << 7;               // m block
  const int kiters = 512 >> 5;                    // K = 512, BK = 32

  const int srow   = lane & 15;
  const int schunk = lane >> 4;
  const int lds_off = schunk * 128 + srow * 8;

  const int fr = lane & 15;
  const int fbase = (lane >> 4) * 128 + fr * 8;
  const int g = lane >> 4;

  const char* Ac = (const char*)A;

  uint32_t aB[2];
  uint32_t bB[2];
  bool bval[2];
  #pragma unroll
  for (int s2 = 0; s2 < 2; ++s2) {
    aB[s2] = (uint32_t)(((size_t)(row0 + (wave + s2 * 4) * 16 + srow) * 512u
                         + (size_t)(schunk * 8)) * 2u);
    int mrow = col0 + (wave + s2 * 4) * 16 + srow;
    bval[s2] = (mrow < count);
    int src = bval[s2] ? idx[mrow] : 0;
    bB[s2] = (uint32_t)(((size_t)src * 512u + (size_t)(schunk * 8)) * 4u);
  }

  f32x4 acc[4][4];
  const f32x4 z = {0.0f, 0.0f, 0.0f, 0.0f};
  #pragma unroll
  for (int i = 0; i < 4; ++i)
    #pragma unroll
    for (int j = 0; j < 4; ++j) acc[i][j] = z;

  bf16x8 rA[2];
  float4 rBlo[2], rBhi[2];
  auto gload = [&](int k0) {
    const uint32_t kb  = (uint32_t)(k0 << 1);
    const uint32_t kbf = (uint32_t)(k0 << 2);
    #pragma unroll
    for (int s2 = 0; s2 < 2; ++s2) rA[s2] = *(const bf16x8*)(Ac + aB[s2] + kb);
    #pragma unroll
    for (int s2 = 0; s2 < 2; ++s2) {
      rBlo[s2] = *(const float4*)((const char*)Bf + bB[s2] + kbf);
      rBhi[s2] = *(const float4*)((const char*)Bf + bB[s2] + kbf + 16);
    }
  };

  const float4 zf = {0.f, 0.f, 0.f, 0.f};
  gload(0);
  for (int it = 0; it < kiters; ++it) {
    const int cur = it & 1;
    #pragma unroll
    for (int s2 = 0; s2 < 2; ++s2)
      *(bf16x8*)&Ah[cur][(wave + s2 * 4) * 512 + lds_off] = rA[s2];
    #pragma unroll
    for (int s2 = 0; s2 < 2; ++s2)
      *(bf16x8*)&Bh[cur][(wave + s2 * 4) * 512 + lds_off] =
          bval[s2] ? cvt8(rBlo[s2], rBhi[s2]) : cvt8(zf, zf);
    if (it + 1 < kiters) gload((it + 1) << 5);
    __syncthreads();

    bf16x8 af[4], bfv[4];
    #pragma unroll
    for (int i = 0; i < 4; ++i)
      af[i] = *(const bf16x8*)&Ah[cur][((wr >> 4) + i) * 512 + fbase];
    #pragma unroll
    for (int j = 0; j < 4; ++j)
      bfv[j] = *(const bf16x8*)&Bh[cur][((wc >> 4) + j) * 512 + fbase];
    #pragma unroll
    for (int i = 0; i < 4; ++i)
      #pragma unroll
      for (int j = 0; j < 4; ++j)
        acc[i][j] = __builtin_amdgcn_mfma_f32_16x16x32_bf16(af[i], bfv[j], acc[i][j], 0, 0, 0);
  }

  #pragma unroll
  for (int i = 0; i < 4; ++i) {
    #pragma unroll
    for (int r = 0; r < 4; ++r) {
      int grow = row0 + wr + i * 16 + g * 4 + r;
      #pragma unroll
      for (int j = 0; j < 4; ++j) {
        int gcol = col0 + wc + j * 16 + fr;
        outh[(size_t)grow * (size_t)M_DIM + gcol] = f2b(acc[i][j][r]);
      }
    }
  }
}

// =============================================================================
// QPROJ GEMM — R6-verified big-tile (BM=128 k, B from hidden fp32, 2-deep
// named-group pipeline, single __syncthreads per K-step).  Unchanged.
// =============================================================================
__global__ __launch_bounds__(512, 2)
void k_qproj(const u16* __restrict__ A, const float* __restrict__ Bf,
             u16* __restrict__ outh, const float* __restrict__ bias,
             float* __restrict__ aux) {
  constexpr int NLA  = 2;
  constexpr int NLB  = 4;
  constexpr int ASUB = 128 * 32;
  constexpr int BSUB = 256 * 32;

  __shared__ u16 Ah[2][128 * 64];
  __shared__ u16 Bh[2][256 * 64];

  const int tid  = threadIdx.x;
  const int wave = tid >> 6, lane = tid & 63;
  const int wave_m = wave >> 2, wave_n = wave & 3;
  const int wm0 = wave_m * 64;
  const int wn0 = wave_n * 64;
  const int fr  = lane & 15, g = lane >> 4;
  const int fbase = g * 128 + fr * 8;

  int id = blockIdx.x + (blockIdx.y << 2);
  int xcd = id & 7, s = id >> 3;
  const int r0 = (xcd * 8 + (s >> 2)) << 8;
  const int m0 = (s & 3) << 7;
  const int kiters = 512 >> 6;

  const char* Ac = (const char*)A;
  uint32_t aB[NLA], bB[NLB];
  #pragma unroll
  for (int s2 = 0; s2 < NLA; ++s2) {
    int ks = s2;                                   // APS=1
    int u  = tid;
    int row = ((u >> 6) << 4) + (u & 15);
    int kch = (u >> 4) & 3;
    aB[s2] = (uint32_t)(((size_t)(m0 + row) * 512u
                         + (size_t)(ks * 32 + kch * 8)) * 2u);
  }
  #pragma unroll
  for (int s2 = 0; s2 < NLB; ++s2) {
    int ks = s2 >> 1;
    int u  = tid + (s2 & 1) * 512;
    int row = ((u >> 6) << 4) + (u & 15);
    int kch = (u >> 4) & 3;
    bB[s2] = (uint32_t)(((size_t)(r0 + row) * 512u
                         + (size_t)(ks * 32 + kch * 8)) * 4u);
  }

  f32x4 acc[4][4];
  const f32x4 z = {0.0f, 0.0f, 0.0f, 0.0f};
  #pragma unroll
  for (int i = 0; i < 4; ++i)
    #pragma unroll
    for (int j = 0; j < 4; ++j) acc[i][j] = z;

  auto gloadA = [&](bf16x8 (&ra)[NLA], int it1) {
    const uint32_t kb = (uint32_t)(it1 << 7);
    #pragma unroll
    for (int s2 = 0; s2 < NLA; ++s2) ra[s2] = *(const bf16x8*)(Ac + aB[s2] + kb);
  };
  auto gloadBf = [&](float4 (&lo)[NLB], float4 (&hi)[NLB], int it1) {
    const uint32_t kb = (uint32_t)(it1 << 8);
    #pragma unroll
    for (int s2 = 0; s2 < NLB; ++s2) {
      lo[s2] = *(const float4*)((const char*)Bf + bB[s2] + kb);
      hi[s2] = *(const float4*)((const char*)Bf + bB[s2] + kb + 16);
    }
  };
  auto commitA = [&](int cur, bf16x8 (&ra)[NLA]) {
    #pragma unroll
    for (int s2 = 0; s2 < NLA; ++s2)
      *(bf16x8*)&Ah[cur][s2 * ASUB + tid * 8] = ra[s2];
  };
  auto commitBf = [&](int cur, float4 (&lo)[NLB], float4 (&hi)[NLB]) {
    #pragma unroll
    for (int s2 = 0; s2 < NLB; ++s2)
      *(bf16x8*)&Bh[cur][(s2 >> 1) * BSUB + (tid + (s2 & 1) * 512) * 8] =
          cvt8(lo[s2], hi[s2]);
  };
  auto compute = [&](int cur) {
    bf16x8 af[4], bfv[4];
    #pragma unroll
    for (int i = 0; i < 4; ++i)
      af[i] = *(const bf16x8*)&Ah[cur][((wm0 >> 4) + i) * 512 + fbase];
    #pragma unroll
    for (int j = 0; j < 4; ++j)
      bfv[j] = *(const bf16x8*)&Bh[cur][((wn0 >> 4) + j) * 512 + fbase];
    #pragma unroll
    for (int i = 0; i < 4; ++i)
      #pragma unroll
      for (int j = 0; j < 4; ++j)
        acc[i][j] = __builtin_amdgcn_mfma_f32_16x16x32_bf16(af[i], bfv[j], acc[i][j], 0, 0, 0);
    #pragma unroll
    for (int i = 0; i < 4; ++i)
      af[i] = *(const bf16x8*)&Ah[cur][ASUB + ((wm0 >> 4) + i) * 512 + fbase];
    #pragma unroll
    for (int j = 0; j < 4; ++j)
      bfv[j] = *(const bf16x8*)&Bh[cur][BSUB + ((wn0 >> 4) + j) * 512 + fbase];
    #pragma unroll
    for (int i = 0; i < 4; ++i)
      #pragma unroll
      for (int j = 0; j < 4; ++j)
        acc[i][j] = __builtin_amdgcn_mfma_f32_16x16x32_bf16(af[i], bfv[j], acc[i][j], 0, 0, 0);
  };

  bf16x8 a0[NLA], a1[NLA];
  float4 b0lo[NLB], b0hi[NLB], b1lo[NLB], b1hi[NLB];
  gloadA(a0, 0); gloadBf(b0lo, b0hi, 0);
  gloadA(a1, 1); gloadBf(b1lo, b1hi, 1);
  for (int it = 0; it < kiters; it += 2) {
    commitA(0, a0); commitBf(0, b0lo, b0hi);
    if (it + 2 < kiters) { gloadA(a0, it + 2); gloadBf(b0lo, b0hi, it + 2); }
    __syncthreads();
    compute(0);
    commitA(1, a1); commitBf(1, b1lo, b1hi);
    if (it + 3 < kiters) { gloadA(a1, it + 3); gloadBf(b1lo, b1hi, it + 3); }
    __syncthreads();
    compute(1);
  }

  float sj[4] = {0.f, 0.f, 0.f, 0.f};
  #pragma unroll
  for (int i = 0; i < 4; ++i) {
    const int kb = m0 + wm0 + i * 16 + g * 4;
    const float4 bkv = *(const float4*)(bias + kb);
    #pragma unroll
    for (int j = 0; j < 4; ++j) {
      const size_t rr = (size_t)(r0 + wn0 + j * 16 + fr);
      float v0 = acc[i][j][0] + bkv.x;
      float v1 = acc[i][j][1] + bkv.y;
      float v2 = acc[i][j][2] + bkv.z;
      float v3 = acc[i][j][3] + bkv.w;
      ushort4 st; st.x = f2b(v0); st.y = f2b(v1); st.z = f2b(v2); st.w = f2b(v3);
      *(ushort4*)(outh + rr * H_DIM + kb) = st;
      sj[j] += v0 * v0 + v1 * v1 + v2 * v2 + v3 * v3;
    }
  }
  const int slot = (m0 + wm0) >> 6;
  #pragma unroll
  for (int j = 0; j < 4; ++j) {
    float s2 = sj[j];
    s2 += __shfl_xor(s2, 16, 64);
    s2 += __shfl_xor(s2, 32, 64);
    if (lane < 16)
      aux[(size_t)(r0 + wn0 + j * 16 + lane) * 8 + slot] = s2;
  }
}

// =============================================================================
// PHASE-SCHEDULED big-tile GEMM (R7): 512 thr = 8 waves, BK=32, 3 LDS buffers,
// 2 named register groups, 4 raw barriers/iter.  Per iteration it (consumes
// buffer it%3):
//   phase A: ds_read half the frags; gload group (it+2)&1 <- tile it+2;
//            s_barrier; lgkmcnt(0)+sched_barrier; setprio(1) MFMA-half
//            setprio(0); s_barrier;
//   phase B: ds_read other half; commit group (it+1)&1 -> buffer (it+1)%3
//            (ds_write; compiler's counted vmcnt targets loads 1.5 iters old);
//            s_barrier; lgkmcnt(0)+sched_barrier; setprio(1) MFMA-half
//            setprio(0); s_barrier;
// The barrier cadence forces the 2 waves/SIMD to alternate LDS-read vs MFMA
// roles (T3 regime); setprio then arbitrates (T5).
// Hazards: commit into b(x) happens >= 1 full iter after all waves' reads of
// b(x) retired (3-buffer rotation); publish = writer's lgkm0 (post-barrier,
// phase B) + 2 more barriers before the first reader; reg groups statically
// named, commit(g) precedes next gload(g) by 1 phase.  No __syncthreads.
//
// EPI3_P  : A=mkn (BM=256 m), B=qb (256 r), K=512. C[m][r] swapped. MF=8.
//           Epilogue: P=(m<count)?exp(10*C*rsqrt(|q|^2+eps)):0; row sums.
// EPI3_OUT: A=MWt (BM=128 h), B=P (256 r), K=meta[1]. C[h][r]. MF=4.
//           Epilogue: out = C*linv[r] + bo[h], coalesced float4.
// =============================================================================
#define EPI3_P   0
#define EPI3_OUT 1

template<int EPI>
__global__ __launch_bounds__(512, 2)
void k_gemm3(const u16* __restrict__ A, const u16* __restrict__ B,
             const int* __restrict__ meta,
             float* __restrict__ outf, u16* __restrict__ outh,
             const float* __restrict__ bias,
             float* __restrict__ aux,
             const float* __restrict__ rowscale) {
  constexpr int BM   = (EPI == EPI3_P) ? 256 : 128; // A rows per tile
  constexpr int MF   = BM / 32;                     // m-frags per wave: 8 / 4
  constexpr int MH   = MF / 2;                      // per-phase m-frags
  constexpr int NF   = 4;                           // r-frags per wave
  constexpr int NLA  = BM / 128;                    // A loads/thread: 2 / 1
  constexpr int NLB  = 2;                           // B loads/thread
  constexpr int AT   = BM * 32;                     // u16 per A tile
  constexpr int BT   = 256 * 32;                    // u16 per B tile

  __shared__ u16 Ah[3][AT];
  __shared__ u16 Bh[3][BT];

  const int tid  = threadIdx.x;
  const int wave = tid >> 6, lane = tid & 63;
  const int wave_m = wave >> 2, wave_n = wave & 3;
  const int wm0 = wave_m * (BM >> 1);
  const int wn0 = wave_n * 64;
  const int fr  = lane & 15, g = lane >> 4;
  const int fbase = g * 128 + fr * 8;

  int m0, r0, kel;
  if (EPI == EPI3_P) {
    int id = blockIdx.x + (blockIdx.y << 4);
    int xcd = id & 7, s = id >> 3;
    r0 = (xcd * 8 + (s >> 4)) << 8;
    m0 = (s & 15) << 8;
    if (m0 >= meta[1]) return;
    kel = 512;
  } else {
    int id = blockIdx.x + (blockIdx.y << 2);
    int xcd = id & 7, s = id >> 3;
    r0 = (xcd * 8 + (s >> 2)) << 8;
    m0 = (s & 3) << 7;
    kel = meta[1];
  }
  const int kiters = kel >> 5;                      // BK=32; multiple of 4
  const int kstr = (EPI == EPI3_OUT) ? M_DIM : 512;

  const char* Ac = (const char*)A;
  const char* Bc = (const char*)B;
  uint32_t aB[NLA], bB[NLB];
  #pragma unroll
  for (int s2 = 0; s2 < NLA; ++s2) {
    int u  = tid + s2 * 512;
    int row = ((u >> 6) << 4) + (u & 15);
    int kch = (u >> 4) & 3;
    aB[s2] = (uint32_t)(((size_t)(m0 + row) * (size_t)kstr
                         + (size_t)(kch * 8)) * 2u);
  }
  #pragma unroll
  for (int s2 = 0; s2 < NLB; ++s2) {
    int u  = tid + s2 * 512;
    int row = ((u >> 6) << 4) + (u & 15);
    int kch = (u >> 4) & 3;
    bB[s2] = (uint32_t)(((size_t)(r0 + row) * (size_t)kstr
                         + (size_t)(kch * 8)) * 2u);
  }

  f32x4 acc[MF][NF];
  const f32x4 z = {0.0f, 0.0f, 0.0f, 0.0f};
  #pragma unroll
  for (int i = 0; i < MF; ++i)
    #pragma unroll
    for (int j = 0; j < NF; ++j) acc[i][j] = z;

  bf16x8 g0a[NLA], g0b[NLB], g1a[NLA], g1b[NLB];

  auto gload = [&](bf16x8 (&ga)[NLA], bf16x8 (&gb)[NLB], int t) {
    const uint32_t kb = (uint32_t)(t << 6);         // 32 k-cols * 2B
    #pragma unroll
    for (int s2 = 0; s2 < NLA; ++s2) ga[s2] = *(const bf16x8*)(Ac + aB[s2] + kb);
    #pragma unroll
    for (int s2 = 0; s2 < NLB; ++s2) gb[s2] = *(const bf16x8*)(Bc + bB[s2] + kb);
  };
  auto commit = [&](int buf, bf16x8 (&ga)[NLA], bf16x8 (&gb)[NLB]) {
    #pragma unroll
    for (int s2 = 0; s2 < NLA; ++s2)
      *(bf16x8*)&Ah[buf][(tid + s2 * 512) * 8] = ga[s2];
    #pragma unroll
    for (int s2 = 0; s2 < NLB; ++s2)
      *(bf16x8*)&Bh[buf][(tid + s2 * 512) * 8] = gb[s2];
  };

  bf16x8 af[MF], bfv[NF];

  #define PHASE_SYNC() do {                                   \
    __builtin_amdgcn_s_barrier();                             \
    asm volatile("s_waitcnt lgkmcnt(0)" ::: "memory");        \
    __builtin_amdgcn_sched_barrier(0);                        \
  } while (0)

  #define MFMA_HALF(base) do {                                \
    __builtin_amdgcn_s_setprio(1);                            \
    _Pragma("unroll")                                         \
    for (int i = 0; i < MH; ++i)                              \
      _Pragma("unroll")                                       \
      for (int j = 0; j < NF; ++j)                            \
        acc[(base) + i][j] = __builtin_amdgcn_mfma_f32_16x16x32_bf16( \
            af[(base) + i], bfv[j], acc[(base) + i][j], 0, 0, 0);    \
    __builtin_amdgcn_s_setprio(0);                            \
    __builtin_amdgcn_s_barrier();                             \
  } while (0)

  // Prologue: stage tile0 -> b0 via g0; load tile1 into g1; publish b0.
  gload(g0a, g0b, 0);
  commit(0, g0a, g0b);                              // vmcnt exposed once
  gload(g1a, g1b, 1);
  asm volatile("s_waitcnt lgkmcnt(0)" ::: "memory");
  __builtin_amdgcn_s_barrier();

  int bc = 0;                                       // buffer of even iter
  for (int it = 0; it < kiters; it += 2) {
    const int b0i = bc;
    const int b1i = (bc + 1 == 3) ? 0 : bc + 1;
    const int b2i = (bc + 2 >= 3) ? bc - 1 : bc + 2;

    // ---------- even iteration (buffer b0i) ----------
    // phase A: frags 0..MH-1 + all B frags; gload g0 <- tile it+2
    #pragma unroll
    for (int i = 0; i < MH; ++i)
      af[i] = *(const bf16x8*)&Ah[b0i][((wm0 >> 4) + i) * 512 + fbase];
    #pragma unroll
    for (int j = 0; j < NF; ++j)
      bfv[j] = *(const bf16x8*)&Bh[b0i][((wn0 >> 4) + j) * 512 + fbase];
    if (it + 2 < kiters) gload(g0a, g0b, it + 2);
    PHASE_SYNC();
    MFMA_HALF(0);
    // phase B: frags MH..MF-1; commit g1 (tile it+1) -> b1i
    #pragma unroll
    for (int i = 0; i < MH; ++i)
      af[MH + i] = *(const bf16x8*)&Ah[b0i][((wm0 >> 4) + MH + i) * 512 + fbase];
    if (it + 1 < kiters) commit(b1i, g1a, g1b);
    PHASE_SYNC();
    MFMA_HALF(MH);

    // ---------- odd iteration (buffer b1i) ----------
    // phase A: gload g1 <- tile it+3
    #pragma unroll
    for (int i = 0; i < MH; ++i)
      af[i] = *(const bf16x8*)&Ah[b1i][((wm0 >> 4) + i) * 512 + fbase];
    #pragma unroll
    for (int j = 0; j < NF; ++j)
      bfv[j] = *(const bf16x8*)&Bh[b1i][((wn0 >> 4) + j) * 512 + fbase];
    if (it + 3 < kiters) gload(g1a, g1b, it + 3);
    PHASE_SYNC();
    MFMA_HALF(0);
    // phase B: commit g0 (tile it+2) -> b2i
    #pragma unroll
    for (int i = 0; i < MH; ++i)
      af[MH + i] = *(const bf16x8*)&Ah[b1i][((wm0 >> 4) + MH + i) * 512 + fbase];
    if (it + 2 < kiters) commit(b2i, g0a, g0b);
    PHASE_SYNC();
    MFMA_HALF(MH);

    bc = (bc + 2 >= 3) ? bc - 1 : bc + 2;
  }

  #undef PHASE_SYNC
  #undef MFMA_HALF

  // Epilogues. C/D layout per 16x16 tile: col = lane&15, row = (lane>>4)*4 + reg.
  if (EPI == EPI3_P) {
    const int count = meta[0];
    float rq10[NF];
    #pragma unroll
    for (int j = 0; j < NF; ++j) {
      const size_t rr = (size_t)(r0 + wn0 + j * 16 + fr);
      float ssum = 0.0f;                            // folded k_rsq
      #pragma unroll
      for (int i = 0; i < 8; ++i) ssum += rowscale[rr * 8 + i];
      rq10[j] = rsqrtf(ssum + 1e-6f) * 10.0f;
    }
    float sj[NF] = {0.f, 0.f, 0.f, 0.f};
    #pragma unroll
    for (int i = 0; i < MF; ++i) {
      const int mb = m0 + wm0 + i * 16 + g * 4;
      #pragma unroll
      for (int j = 0; j < NF; ++j) {
        const size_t rr = (size_t)(r0 + wn0 + j * 16 + fr);
        float p0 = (mb + 0 < count) ? __expf(acc[i][j][0] * rq10[j]) : 0.0f;
        float p1 = (mb + 1 < count) ? __expf(acc[i][j][1] * rq10[j]) : 0.0f;
        float p2 = (mb + 2 < count) ? __expf(acc[i][j][2] * rq10[j]) : 0.0f;
        float p3 = (mb + 3 < count) ? __expf(acc[i][j][3] * rq10[j]) : 0.0f;
        ushort4 st; st.x = f2b(p0); st.y = f2b(p1); st.z = f2b(p2); st.w = f2b(p3);
        *(ushort4*)(outh + rr * M_DIM + mb) = st;   // packed 8B, [r][m]
        sj[j] += (p0 + p1) + (p2 + p3);
      }
    }
    const int slot = (m0 + wm0) >> 6;
    #pragma unroll
    for (int j = 0; j < NF; ++j) {
      float s = sj[j];
      s += __shfl_xor(s, 16, 64);
      s += __shfl_xor(s, 32, 64);
      if (lane < 16) {
        const size_t rr = (size_t)(r0 + wn0 + j * 16 + lane);
        aux[rr * 64 + slot]     = s;
        aux[rr * 64 + slot + 1] = 0.0f;
      }
    }
  } else { // EPI3_OUT
    float scl[NF];
    #pragma unroll
    for (int j = 0; j < NF; ++j)
      scl[j] = rowscale[r0 + wn0 + j * 16 + fr];
    #pragma unroll
    for (int i = 0; i < MF; ++i) {
      const int hb = m0 + wm0 + i * 16 + g * 4;
      const float4 bv = *(const float4*)(bias + hb);
      #pragma unroll
      for (int j = 0; j < NF; ++j) {
        const size_t rr = (size_t)(r0 + wn0 + j * 16 + fr);
        float4 o;
        o.x = acc[i][j][0] * scl[j] + bv.x;
        o.y = acc[i][j][1] * scl[j] + bv.y;
        o.z = acc[i][j][2] * scl[j] + bv.z;
        o.w = acc[i][j][3] * scl[j] + bv.w;
        *(float4*)(outf + rr * H_DIM + hb) = o;
      }
    }
  }
}

extern "C" void kernel_launch(void* const* d_in, const int* in_sizes, int n_in,
                              void* d_out, int out_size, void* d_ws, size_t ws_size,
                              hipStream_t stream) {
  const float* hidden = (const float*)d_in[0];   // [16384, 512]
  const float* mkeys  = (const float*)d_in[1];   // [4096, 512]
  const float* mvals  = (const float*)d_in[2];   // [4096, 512]
  const float* Wk     = (const float*)d_in[3];   // [512, 512]
  const float* bk     = (const float*)d_in[4];   // [512]
  const float* Wo     = (const float*)d_in[5];   // [512, 512]
  const float* bo     = (const float*)d_in[6];   // [512]
  const int*   usage  = (const int*)d_in[7];     // [4096]
  (void)in_sizes; (void)n_in; (void)out_size; (void)ws_size;

  char* ws = (char*)d_ws;
  int*   idx   = (int*)(ws + 0);            //      16,384  compacted->orig map
  int*   meta  = (int*)(ws + 16384);        //          16  {count, K_eff, K/32, K/128}
  float* lpart = (float*)(ws + 1048576);    //   4,194,304  row-sum partials [16384,64]
  float* qss   = (float*)(ws + 5242880);    //     524,288  q sumsq partials [16384,8]
  u16*   wkb   = (u16*)(ws + 16777216);     //     524,288  Wk bf16
  u16*   wob   = (u16*)(ws + 17301504);     //     524,288  Wo bf16
  u16*   mkn   = (u16*)(ws + 17825792);     //   4,194,304  compacted normalized keys bf16
  u16*   qb    = (u16*)(ws + 26214400);     //  16,777,216  q bf16 [r][k]
  u16*   MWt   = (u16*)(ws + 42991616);     //   4,194,304  (mvals@Wo^T)^T bf16 [512,4096]
  u16*   P     = (u16*)(ws + 47185920);     // 134,217,728  exp-scores bf16 [16384,4096]
  float* linv  = (float*)(ws + 183828480);  //      65,536  1/rowsum [16384]

  // weight casts (Wk, Wo)
  k_f2bf_ww<<<512, 256, 0, stream>>>(Wk, Wo, wkb, wob);

  // compaction of the memory bank
  k_compact<<<1, 256, 0, stream>>>(usage, idx, meta);
  k_gather_keys<<<1024, 256, 0, stream>>>(mkeys, idx, meta, mkn);

  // q[r,k] = hidden @ Wk^T + bk, swapped C[k,r]; B staged from fp32 hidden
  k_qproj<<<dim3(4, 64), 512, 0, stream>>>(wkb, hidden, qb, bk, qss);

  // MWt[h, m] = sum_v Wo[h,v] * mvals[idx[m],v]  (values gather fused)
  k_gemm_mw<<<dim3(16, 4), 256, 0, stream>>>(wob, mvals, idx, meta, MWt);

  // P[r,m] = exp(10 * (qb @ mkn^T) * rsqrt(|q_r|^2+eps)) — phase-scheduled
  k_gemm3<EPI3_P><<<dim3(16, 64), 512, 0, stream>>>(mkn, qb, meta,
      nullptr, P, nullptr, lpart, qss);
  k_reduce_l<<<64, 256, 0, stream>>>(lpart, linv, meta);

  // out[r,h] = (P @ MWt^T)*linv[r] + bo — phase-scheduled
  k_gemm3<EPI3_OUT><<<dim3(4, 64), 512, 0, stream>>>(MWt, P, meta,
      (float*)d_out, nullptr, bo, nullptr, linv);
}

// Round 8
// 245.533 us; speedup vs baseline: 1.1176x; 1.1176x over previous
//
#include <hip/hip_runtime.h>
#include <cstdint>
#include <cstddef>

// Problem constants: B=8, S=2048, H=512, M=4096 -> R = B*S = 16384 rows.
#define H_DIM   512
#define M_DIM   4096

typedef unsigned short u16;
typedef short bf16x8 __attribute__((ext_vector_type(8)));   // 8 bf16 in 4 VGPRs
typedef float f32x4  __attribute__((ext_vector_type(4)));

// fp32 -> bf16 round-to-nearest-even
__device__ __forceinline__ u16 f2b(float f) {
  union { float f; uint32_t u; } v; v.f = f;
  uint32_t u = v.u + (0x7FFFu + ((v.u >> 16) & 1u));
  return (u16)(u >> 16);
}

// pack 8 fp32 (two float4) -> bf16x8
__device__ __forceinline__ bf16x8 cvt8(const float4& lo, const float4& hi) {
  union { u16 u[8]; bf16x8 v; } o;
  o.u[0] = f2b(lo.x); o.u[1] = f2b(lo.y); o.u[2] = f2b(lo.z); o.u[3] = f2b(lo.w);
  o.u[4] = f2b(hi.x); o.u[5] = f2b(hi.y); o.u[6] = f2b(hi.z); o.u[7] = f2b(hi.w);
  return o.v;
}

// =============================================================================
// Fused init: blocks 0..511 cast Wk,Wo -> bf16; block 512 compacts usage;
// blocks 513..528 zero lsum[16384].  Block-uniform branching.
// meta[0]=count, meta[1]=K_eff=round128(count), meta[2]=K_eff/32, meta[3]=K_eff/128
// =============================================================================
__global__ void k_init(const float* __restrict__ wk, const float* __restrict__ wo,
                       u16* __restrict__ owk, u16* __restrict__ owo,
                       const int* __restrict__ usage, int* __restrict__ idx,
                       int* __restrict__ meta, float* __restrict__ lsum) {
  __shared__ int cnt[256];
  const int blk = blockIdx.x;
  const int t = threadIdx.x;
  if (blk < 512) {                                  // weight casts
    int i = blk * 256 + t;
    const float* src = (i < 65536) ? wk : wo;
    u16* dst = (i < 65536) ? owk : owo;
    int j = i & 65535;
    float4 v = ((const float4*)src)[j];
    ushort4 o;
    o.x = f2b(v.x); o.y = f2b(v.y); o.z = f2b(v.z); o.w = f2b(v.w);
    ((ushort4*)dst)[j] = o;
  } else if (blk == 512) {                          // compaction scan
    int base = t * 16;
    int c = 0;
    #pragma unroll
    for (int i = 0; i < 16; ++i) c += (usage[base + i] > 0) ? 1 : 0;
    cnt[t] = c;
    __syncthreads();
    for (int d = 1; d < 256; d <<= 1) {             // inclusive Hillis-Steele
      int v = (t >= d) ? cnt[t - d] : 0;
      __syncthreads();
      cnt[t] += v;
      __syncthreads();
    }
    int pos = cnt[t] - c;                           // exclusive prefix
    for (int i = 0; i < 16; ++i)
      if (usage[base + i] > 0) idx[pos++] = base + i;
    if (t == 0) {
      int total = cnt[255];
      int keff = ((total + 127) >> 7) << 7;         // 128-granular padding
      meta[0] = total; meta[1] = keff; meta[2] = keff >> 5; meta[3] = keff >> 7;
    }
  } else {                                          // zero lsum (16 blocks)
    int i = (blk - 513) * 256 + t;                  // 16*256 float4 = 16384 f
    float4 zf = {0.f, 0.f, 0.f, 0.f};
    ((float4*)lsum)[i] = zf;
  }
}

// ---- gather keys: L2-normalized, compacted -> bf16 (keys ONLY) --------------
// Zero-pads rows j in [count, 4096) (256-row tiles may read them).
__global__ void k_gather_keys(const float* __restrict__ keys,
                              const int* __restrict__ idx, const int* __restrict__ meta,
                              u16* __restrict__ okeys) {
  int j    = blockIdx.x * 4 + (threadIdx.x >> 6);
  int lane = threadIdx.x & 63;
  int count = meta[0];
  ushort4* kp = (ushort4*)(okeys + (size_t)j * H_DIM);
  if (j >= count) {                 // wave-uniform
    ushort4 z = {0, 0, 0, 0};
    kp[lane] = z; kp[lane + 64] = z;
    return;
  }
  int src = idx[j];
  const float4* rp = (const float4*)(keys + (size_t)src * H_DIM);
  float4 a = rp[lane];
  float4 b = rp[lane + 64];
  float ss = a.x*a.x + a.y*a.y + a.z*a.z + a.w*a.w
           + b.x*b.x + b.y*b.y + b.z*b.z + b.w*b.w;
  #pragma unroll
  for (int d = 1; d < 64; d <<= 1) ss += __shfl_xor(ss, d, 64);
  float s = rsqrtf(ss + 1e-6f);
  ushort4 oa, ob;
  oa.x = f2b(a.x*s); oa.y = f2b(a.y*s); oa.z = f2b(a.z*s); oa.w = f2b(a.w*s);
  ob.x = f2b(b.x*s); ob.y = f2b(b.y*s); ob.z = f2b(b.z*s); ob.w = f2b(b.w*s);
  kp[lane]      = oa;
  kp[lane + 64] = ob;
}

// =============================================================================
// MW GEMM (128x128, 256 thr, 4 waves): MWt[h,m] = sum_v Wo[h,v]*mvals[idx[m],v]
// values gather + cast fused into B staging.  Unchanged from R6 (verified).
// =============================================================================
__global__ __launch_bounds__(256, 3)
void k_gemm_mw(const u16* __restrict__ A, const float* __restrict__ Bf,
               const int* __restrict__ idx, const int* __restrict__ meta,
               u16* __restrict__ outh) {
  __shared__ u16 Ah[2][128 * 32];
  __shared__ u16 Bh[2][128 * 32];

  const int tid  = threadIdx.x;
  const int wave = tid >> 6, lane = tid & 63;
  const int wr = (wave >> 1) * 64;
  const int wc = (wave & 1) * 64;

  const int count = meta[0];
  if (blockIdx.x >= (meta[1] >> 7)) return;       // inactive m-block
  const int row0 = blockIdx.y << 7;               // h block
  const int col0 = blockIdx.x << 7;               // m block
  const int kiters = 512 >> 5;                    // K = 512, BK = 32

  const int srow   = lane & 15;
  const int schunk = lane >> 4;
  const int lds_off = schunk * 128 + srow * 8;

  const int fr = lane & 15;
  const int fbase = (lane >> 4) * 128 + fr * 8;
  const int g = lane >> 4;

  const char* Ac = (const char*)A;

  uint32_t aB[2];
  uint32_t bB[2];
  bool bval[2];
  #pragma unroll
  for (int s2 = 0; s2 < 2; ++s2) {
    aB[s2] = (uint32_t)(((size_t)(row0 + (wave + s2 * 4) * 16 + srow) * 512u
                         + (size_t)(schunk * 8)) * 2u);
    int mrow = col0 + (wave + s2 * 4) * 16 + srow;
    bval[s2] = (mrow < count);
    int src = bval[s2] ? idx[mrow] : 0;
    bB[s2] = (uint32_t)(((size_t)src * 512u + (size_t)(schunk * 8)) * 4u);
  }

  f32x4 acc[4][4];
  const f32x4 z = {0.0f, 0.0f, 0.0f, 0.0f};
  #pragma unroll
  for (int i = 0; i < 4; ++i)
    #pragma unroll
    for (int j = 0; j < 4; ++j) acc[i][j] = z;

  bf16x8 rA[2];
  float4 rBlo[2], rBhi[2];
  auto gload = [&](int k0) {
    const uint32_t kb  = (uint32_t)(k0 << 1);
    const uint32_t kbf = (uint32_t)(k0 << 2);
    #pragma unroll
    for (int s2 = 0; s2 < 2; ++s2) rA[s2] = *(const bf16x8*)(Ac + aB[s2] + kb);
    #pragma unroll
    for (int s2 = 0; s2 < 2; ++s2) {
      rBlo[s2] = *(const float4*)((const char*)Bf + bB[s2] + kbf);
      rBhi[s2] = *(const float4*)((const char*)Bf + bB[s2] + kbf + 16);
    }
  };

  const float4 zf = {0.f, 0.f, 0.f, 0.f};
  gload(0);
  for (int it = 0; it < kiters; ++it) {
    const int cur = it & 1;
    #pragma unroll
    for (int s2 = 0; s2 < 2; ++s2)
      *(bf16x8*)&Ah[cur][(wave + s2 * 4) * 512 + lds_off] = rA[s2];
    #pragma unroll
    for (int s2 = 0; s2 < 2; ++s2)
      *(bf16x8*)&Bh[cur][(wave + s2 * 4) * 512 + lds_off] =
          bval[s2] ? cvt8(rBlo[s2], rBhi[s2]) : cvt8(zf, zf);
    if (it + 1 < kiters) gload((it + 1) << 5);
    __syncthreads();

    bf16x8 af[4], bfv[4];
    #pragma unroll
    for (int i = 0; i < 4; ++i)
      af[i] = *(const bf16x8*)&Ah[cur][((wr >> 4) + i) * 512 + fbase];
    #pragma unroll
    for (int j = 0; j < 4; ++j)
      bfv[j] = *(const bf16x8*)&Bh[cur][((wc >> 4) + j) * 512 + fbase];
    #pragma unroll
    for (int i = 0; i < 4; ++i)
      #pragma unroll
      for (int j = 0; j < 4; ++j)
        acc[i][j] = __builtin_amdgcn_mfma_f32_16x16x32_bf16(af[i], bfv[j], acc[i][j], 0, 0, 0);
  }

  #pragma unroll
  for (int i = 0; i < 4; ++i) {
    #pragma unroll
    for (int r = 0; r < 4; ++r) {
      int grow = row0 + wr + i * 16 + g * 4 + r;
      #pragma unroll
      for (int j = 0; j < 4; ++j) {
        int gcol = col0 + wc + j * 16 + fr;
        outh[(size_t)grow * (size_t)M_DIM + gcol] = f2b(acc[i][j][r]);
      }
    }
  }
}

// =============================================================================
// Big-tile BT GEMM — EXACT R6 CORE (verified 252.5 µs config).  512 thr =
// 8 waves (2Mx4N), BK=64, reg-staged single-barrier double buffer; loads
// issued right after ds_write commit, BEFORE the barrier.  MF=4 kernels
// (OUT, QPROJ) use the 2-deep named-group pipeline; P (MF=8) stays 1-deep.
// QPROJ stages B directly from hidden fp32.
//
// R8 epilogue changes ONLY:
//   EPI2_P  : row-sum partials -> atomicAdd(lsum[r]) (k_reduce_l eliminated)
//   EPI2_OUT: rowscale = lsum; scl = 1/lsum[r] inline
// =============================================================================
#define EPI2_P     0
#define EPI2_OUT   1
#define EPI2_QPROJ 2

template<int EPI>
__global__ __launch_bounds__(512, 2)
void k_gemm2(const u16* __restrict__ A, const u16* __restrict__ B,
             const int* __restrict__ meta,
             float* __restrict__ outf, u16* __restrict__ outh,
             const float* __restrict__ bias,
             float* __restrict__ aux,
             const float* __restrict__ rowscale) {
  constexpr int BM   = (EPI == EPI2_P) ? 256 : 128; // A rows per tile
  constexpr int MF   = BM / 32;                     // m-frags per wave: 8 / 4
  constexpr int NF   = 4;                           // r-frags per wave
  constexpr int APS  = BM / 128;                    // A loads per sub-tile: 2 / 1
  constexpr int NLA  = BM / 64;                     // A loads per thread: 4 / 2
  constexpr int NLB  = 4;                           // B loads per thread
  constexpr int ASUB = BM * 32;                     // u16 per A sub-tile
  constexpr int BSUB = 256 * 32;                    // u16 per B sub-tile
  constexpr bool BF32 = (EPI == EPI2_QPROJ);        // B staged from fp32

  __shared__ u16 Ah[2][BM * 64];
  __shared__ u16 Bh[2][256 * 64];

  const int tid  = threadIdx.x;
  const int wave = tid >> 6, lane = tid & 63;
  const int wave_m = wave >> 2, wave_n = wave & 3;
  const int wm0 = wave_m * (BM >> 1);               // wave m-offset
  const int wn0 = wave_n * 64;                      // wave r-offset
  const int fr  = lane & 15, g = lane >> 4;
  const int fbase = g * 128 + fr * 8;               // fragment LDS offset (u16)

  int m0, r0, kel;
  if (EPI == EPI2_P) {
    // grid (16,64): XCD-swizzled; all 16 m-blocks of 8 r-blocks per XCD
    int id = blockIdx.x + (blockIdx.y << 4);
    int xcd = id & 7, s = id >> 3;
    r0 = (xcd * 8 + (s >> 4)) << 8;
    m0 = (s & 15) << 8;
    if (m0 >= meta[1]) return;                      // inactive m-block
    kel = 512;
  } else if (EPI == EPI2_OUT) {
    // grid (4,64): XCD-swizzled; the 4 h-blocks of 8 r-blocks per XCD
    int id = blockIdx.x + (blockIdx.y << 2);
    int xcd = id & 7, s = id >> 3;
    r0 = (xcd * 8 + (s >> 2)) << 8;
    m0 = (s & 3) << 7;                              // h0
    kel = meta[1];
  } else { // EPI2_QPROJ — same block geometry as OUT, m0 = k-block
    int id = blockIdx.x + (blockIdx.y << 2);
    int xcd = id & 7, s = id >> 3;
    r0 = (xcd * 8 + (s >> 2)) << 8;
    m0 = (s & 3) << 7;
    kel = 512;
  }
  const int kiters = kel >> 6;                      // always even (kel 128-granular)
  if (kiters <= 0) return;
  const int kstr = (EPI == EPI2_OUT) ? M_DIM : 512; // row stride (elements)

  // staging: A load s2 -> sub-tile s2/APS, unit tid + (s2%APS)*512
  //          B load s2 -> sub-tile s2>>1,  unit tid + (s2&1)*512
  const char* Ac = (const char*)A;
  const char* Bc = (const char*)B;                  // u16 or fp32 base
  uint32_t aB[NLA], bB[NLB];
  #pragma unroll
  for (int s2 = 0; s2 < NLA; ++s2) {
    int ks = s2 / APS;
    int u  = tid + (s2 % APS) * 512;
    int row = ((u >> 6) << 4) + (u & 15);
    int kch = (u >> 4) & 3;
    aB[s2] = (uint32_t)(((size_t)(m0 + row) * (size_t)kstr
                         + (size_t)(ks * 32 + kch * 8)) * 2u);
  }
  #pragma unroll
  for (int s2 = 0; s2 < NLB; ++s2) {
    int ks = s2 >> 1;
    int u  = tid + (s2 & 1) * 512;
    int row = ((u >> 6) << 4) + (u & 15);
    int kch = (u >> 4) & 3;
    bB[s2] = (uint32_t)(((size_t)(r0 + row) * (size_t)kstr
                         + (size_t)(ks * 32 + kch * 8)) * (BF32 ? 4u : 2u));
  }

  f32x4 acc[MF][NF];
  const f32x4 z = {0.0f, 0.0f, 0.0f, 0.0f};
  #pragma unroll
  for (int i = 0; i < MF; ++i)
    #pragma unroll
    for (int j = 0; j < NF; ++j) acc[i][j] = z;

  auto gloadA = [&](bf16x8 (&ra)[NLA], int it1) {
    const uint32_t kb = (uint32_t)(it1 << 7);       // 64 k-cols * 2B
    #pragma unroll
    for (int s2 = 0; s2 < NLA; ++s2) ra[s2] = *(const bf16x8*)(Ac + aB[s2] + kb);
  };
  auto gloadBh = [&](bf16x8 (&rb)[NLB], int it1) {
    const uint32_t kb = (uint32_t)(it1 << 7);
    #pragma unroll
    for (int s2 = 0; s2 < NLB; ++s2) rb[s2] = *(const bf16x8*)(Bc + bB[s2] + kb);
  };
  auto gloadBf = [&](float4 (&lo)[NLB], float4 (&hi)[NLB], int it1) {
    const uint32_t kb = (uint32_t)(it1 << 8);       // 64 k-cols * 4B
    #pragma unroll
    for (int s2 = 0; s2 < NLB; ++s2) {
      lo[s2] = *(const float4*)(Bc + bB[s2] + kb);
      hi[s2] = *(const float4*)(Bc + bB[s2] + kb + 16);
    }
  };
  auto commitA = [&](int cur, bf16x8 (&ra)[NLA]) {
    #pragma unroll
    for (int s2 = 0; s2 < NLA; ++s2)
      *(bf16x8*)&Ah[cur][(s2 / APS) * ASUB + (tid + (s2 % APS) * 512) * 8] = ra[s2];
  };
  auto commitBh = [&](int cur, bf16x8 (&rb)[NLB]) {
    #pragma unroll
    for (int s2 = 0; s2 < NLB; ++s2)
      *(bf16x8*)&Bh[cur][(s2 >> 1) * BSUB + (tid + (s2 & 1) * 512) * 8] = rb[s2];
  };
  auto commitBf = [&](int cur, float4 (&lo)[NLB], float4 (&hi)[NLB]) {
    #pragma unroll
    for (int s2 = 0; s2 < NLB; ++s2)
      *(bf16x8*)&Bh[cur][(s2 >> 1) * BSUB + (tid + (s2 & 1) * 512) * 8] =
          cvt8(lo[s2], hi[s2]);
  };
  auto compute = [&](int cur) {
    bf16x8 af[MF], bfv[NF];
    // k-substep 0
    #pragma unroll
    for (int i = 0; i < MF; ++i)
      af[i] = *(const bf16x8*)&Ah[cur][((wm0 >> 4) + i) * 512 + fbase];
    #pragma unroll
    for (int j = 0; j < NF; ++j)
      bfv[j] = *(const bf16x8*)&Bh[cur][((wn0 >> 4) + j) * 512 + fbase];
    #pragma unroll
    for (int i = 0; i < MF; ++i)
      #pragma unroll
      for (int j = 0; j < NF; ++j)
        acc[i][j] = __builtin_amdgcn_mfma_f32_16x16x32_bf16(af[i], bfv[j], acc[i][j], 0, 0, 0);
    // k-substep 1
    #pragma unroll
    for (int i = 0; i < MF; ++i)
      af[i] = *(const bf16x8*)&Ah[cur][ASUB + ((wm0 >> 4) + i) * 512 + fbase];
    #pragma unroll
    for (int j = 0; j < NF; ++j)
      bfv[j] = *(const bf16x8*)&Bh[cur][BSUB + ((wn0 >> 4) + j) * 512 + fbase];
    #pragma unroll
    for (int i = 0; i < MF; ++i)
      #pragma unroll
      for (int j = 0; j < NF; ++j)
        acc[i][j] = __builtin_amdgcn_mfma_f32_16x16x32_bf16(af[i], bfv[j], acc[i][j], 0, 0, 0);
  };

  if constexpr (EPI == EPI2_P) {
    // 1-deep pipeline: commit; refill; barrier; compute.
    bf16x8 rA[NLA], rB[NLB];
    gloadA(rA, 0); gloadBh(rB, 0);
    for (int it = 0; it < kiters; ++it) {
      const int cur = it & 1;
      commitA(cur, rA); commitBh(cur, rB);
      if (it + 1 < kiters) { gloadA(rA, it + 1); gloadBh(rB, it + 1); }
      __syncthreads();                              // lgkmcnt only
      compute(cur);
    }
  } else if constexpr (!BF32) { // EPI2_OUT
    // 2-deep pipeline: named groups, 2-iter unrolled.
    bf16x8 a0[NLA], b0[NLB], a1[NLA], b1[NLB];
    gloadA(a0, 0); gloadBh(b0, 0);
    if (kiters > 1) { gloadA(a1, 1); gloadBh(b1, 1); }
    for (int it = 0; it < kiters; it += 2) {
      commitA(0, a0); commitBh(0, b0);
      if (it + 2 < kiters) { gloadA(a0, it + 2); gloadBh(b0, it + 2); }
      __syncthreads();
      compute(0);
      commitA(1, a1); commitBh(1, b1);
      if (it + 3 < kiters) { gloadA(a1, it + 3); gloadBh(b1, it + 3); }
      __syncthreads();
      compute(1);
    }
  } else { // EPI2_QPROJ — 2-deep, B from fp32
    bf16x8 a0[NLA], a1[NLA];
    float4 b0lo[NLB], b0hi[NLB], b1lo[NLB], b1hi[NLB];
    gloadA(a0, 0); gloadBf(b0lo, b0hi, 0);
    if (kiters > 1) { gloadA(a1, 1); gloadBf(b1lo, b1hi, 1); }
    for (int it = 0; it < kiters; it += 2) {
      commitA(0, a0); commitBf(0, b0lo, b0hi);
      if (it + 2 < kiters) { gloadA(a0, it + 2); gloadBf(b0lo, b0hi, it + 2); }
      __syncthreads();
      compute(0);
      commitA(1, a1); commitBf(1, b1lo, b1hi);
      if (it + 3 < kiters) { gloadA(a1, it + 3); gloadBf(b1lo, b1hi, it + 3); }
      __syncthreads();
      compute(1);
    }
  }

  // Epilogues. C/D layout per 16x16 tile: col = lane&15, row = (lane>>4)*4 + reg.
  if (EPI == EPI2_P) {
    const int count = meta[0];
    float rq10[NF];
    #pragma unroll
    for (int j = 0; j < NF; ++j) {
      const size_t rr = (size_t)(r0 + wn0 + j * 16 + fr);
      float ssum = 0.0f;                            // folded k_rsq
      #pragma unroll
      for (int i = 0; i < 8; ++i) ssum += rowscale[rr * 8 + i];
      rq10[j] = rsqrtf(ssum + 1e-6f) * 10.0f;
    }
    float sj[NF] = {0.f, 0.f, 0.f, 0.f};
    #pragma unroll
    for (int i = 0; i < MF; ++i) {
      const int mb = m0 + wm0 + i * 16 + g * 4;     // 4 consecutive m
      #pragma unroll
      for (int j = 0; j < NF; ++j) {
        const size_t rr = (size_t)(r0 + wn0 + j * 16 + fr);
        float p0 = (mb + 0 < count) ? __expf(acc[i][j][0] * rq10[j]) : 0.0f;
        float p1 = (mb + 1 < count) ? __expf(acc[i][j][1] * rq10[j]) : 0.0f;
        float p2 = (mb + 2 < count) ? __expf(acc[i][j][2] * rq10[j]) : 0.0f;
        float p3 = (mb + 3 < count) ? __expf(acc[i][j][3] * rq10[j]) : 0.0f;
        ushort4 st; st.x = f2b(p0); st.y = f2b(p1); st.z = f2b(p2); st.w = f2b(p3);
        *(ushort4*)(outh + rr * M_DIM + mb) = st;   // packed 8B, [r][m]
        sj[j] += (p0 + p1) + (p2 + p3);
      }
    }
    // per-wave row-sum partial -> atomic accumulate (k_reduce_l eliminated)
    #pragma unroll
    for (int j = 0; j < NF; ++j) {
      float s = sj[j];
      s += __shfl_xor(s, 16, 64);
      s += __shfl_xor(s, 32, 64);
      if (lane < 16)
        atomicAdd(&aux[(size_t)(r0 + wn0 + j * 16 + lane)], s);
    }
  } else if (EPI == EPI2_OUT) {
    float scl[NF];
    #pragma unroll
    for (int j = 0; j < NF; ++j)
      scl[j] = 1.0f / rowscale[r0 + wn0 + j * 16 + fr];   // linv inline
    #pragma unroll
    for (int i = 0; i < MF; ++i) {
      const int hb = m0 + wm0 + i * 16 + g * 4;     // 4 consecutive h
      const float4 bv = *(const float4*)(bias + hb);
      #pragma unroll
      for (int j = 0; j < NF; ++j) {
        const size_t rr = (size_t)(r0 + wn0 + j * 16 + fr);
        float4 o;
        o.x = acc[i][j][0] * scl[j] + bv.x;
        o.y = acc[i][j][1] * scl[j] + bv.y;
        o.z = acc[i][j][2] * scl[j] + bv.z;
        o.w = acc[i][j][3] * scl[j] + bv.w;
        *(float4*)(outf + rr * H_DIM + hb) = o;     // coalesced 16B store
      }
    }
  } else { // EPI2_QPROJ
    float sj[NF] = {0.f, 0.f, 0.f, 0.f};
    #pragma unroll
    for (int i = 0; i < MF; ++i) {
      const int kb = m0 + wm0 + i * 16 + g * 4;     // 4 consecutive k
      const float4 bkv = *(const float4*)(bias + kb);
      #pragma unroll
      for (int j = 0; j < NF; ++j) {
        const size_t rr = (size_t)(r0 + wn0 + j * 16 + fr);
        float v0 = acc[i][j][0] + bkv.x;
        float v1 = acc[i][j][1] + bkv.y;
        float v2 = acc[i][j][2] + bkv.z;
        float v3 = acc[i][j][3] + bkv.w;
        ushort4 st; st.x = f2b(v0); st.y = f2b(v1); st.z = f2b(v2); st.w = f2b(v3);
        *(ushort4*)(outh + rr * H_DIM + kb) = st;   // packed 8B, [r][k]
        sj[j] += v0 * v0 + v1 * v1 + v2 * v2 + v3 * v3;
      }
    }
    const int slot = (m0 + wm0) >> 6;               // 0..7
    #pragma unroll
    for (int j = 0; j < NF; ++j) {
      float s = sj[j];
      s += __shfl_xor(s, 16, 64);
      s += __shfl_xor(s, 32, 64);
      if (lane < 16)
        aux[(size_t)(r0 + wn0 + j * 16 + lane) * 8 + slot] = s;
    }
  }
}

extern "C" void kernel_launch(void* const* d_in, const int* in_sizes, int n_in,
                              void* d_out, int out_size, void* d_ws, size_t ws_size,
                              hipStream_t stream) {
  const float* hidden = (const float*)d_in[0];   // [16384, 512]
  const float* mkeys  = (const float*)d_in[1];   // [4096, 512]
  const float* mvals  = (const float*)d_in[2];   // [4096, 512]
  const float* Wk     = (const float*)d_in[3];   // [512, 512]
  const float* bk     = (const float*)d_in[4];   // [512]
  const float* Wo     = (const float*)d_in[5];   // [512, 512]
  const float* bo     = (const float*)d_in[6];   // [512]
  const int*   usage  = (const int*)d_in[7];     // [4096]
  (void)in_sizes; (void)n_in; (void)out_size; (void)ws_size;

  char* ws = (char*)d_ws;
  int*   idx   = (int*)(ws + 0);            //      16,384  compacted->orig map
  int*   meta  = (int*)(ws + 16384);        //          16  {count, K_eff, K/32, K/128}
  float* lsum  = (float*)(ws + 1048576);    //      65,536  softmax row sums [16384]
  float* qss   = (float*)(ws + 5242880);    //     524,288  q sumsq partials [16384,8]
  u16*   wkb   = (u16*)(ws + 16777216);     //     524,288  Wk bf16
  u16*   wob   = (u16*)(ws + 17301504);     //     524,288  Wo bf16
  u16*   mkn   = (u16*)(ws + 17825792);     //   4,194,304  compacted normalized keys bf16
  u16*   qb    = (u16*)(ws + 26214400);     //  16,777,216  q bf16 [r][k]
  u16*   MWt   = (u16*)(ws + 42991616);     //   4,194,304  (mvals@Wo^T)^T bf16 [512,4096]
  u16*   P     = (u16*)(ws + 47185920);     // 134,217,728  exp-scores bf16 [16384,4096]

  // fused: weight casts + compaction + lsum zeroing (blocks 0-511 | 512 | 513-528)
  k_init<<<529, 256, 0, stream>>>(Wk, Wo, wkb, wob, usage, idx, meta, lsum);

  k_gather_keys<<<1024, 256, 0, stream>>>(mkeys, idx, meta, mkn);

  // q[r,k] = hidden @ Wk^T + bk, swapped C[k,r]; B staged from fp32 hidden
  k_gemm2<EPI2_QPROJ><<<dim3(4, 64), 512, 0, stream>>>(wkb, (const u16*)hidden,
      nullptr, nullptr, qb, bk, qss, nullptr);

  // MWt[h, m] = sum_v Wo[h,v] * mvals[idx[m],v]  (values gather fused)
  k_gemm_mw<<<dim3(16, 4), 256, 0, stream>>>(wob, mvals, idx, meta, MWt);

  // P[r,m] = exp(10 * (qb @ mkn^T) * rsqrt(|q_r|^2+eps)); row sums -> lsum atomics
  k_gemm2<EPI2_P><<<dim3(16, 64), 512, 0, stream>>>(mkn, qb, meta,
      nullptr, P, nullptr, lsum, qss);

  // out[r,h] = (P @ MWt^T) / lsum[r] + bo — division folded into epilogue
  k_gemm2<EPI2_OUT><<<dim3(4, 64), 512, 0, stream>>>(MWt, P, meta,
      (float*)d_out, nullptr, bo, nullptr, lsum);
}

// Round 9
// 243.618 us; speedup vs baseline: 1.1264x; 1.0079x over previous
//
#include <hip/hip_runtime.h>
#include <cstdint>
#include <cstddef>

// Problem constants: B=8, S=2048, H=512, M=4096 -> R = B*S = 16384 rows.
#define H_DIM   512
#define M_DIM   4096

typedef unsigned short u16;
typedef short bf16x8 __attribute__((ext_vector_type(8)));   // 8 bf16 in 4 VGPRs
typedef float f32x4  __attribute__((ext_vector_type(4)));

// fp32 -> bf16 round-to-nearest-even
__device__ __forceinline__ u16 f2b(float f) {
  union { float f; uint32_t u; } v; v.f = f;
  uint32_t u = v.u + (0x7FFFu + ((v.u >> 16) & 1u));
  return (u16)(u >> 16);
}

// pack 8 fp32 (two float4) -> bf16x8
__device__ __forceinline__ bf16x8 cvt8(const float4& lo, const float4& hi) {
  union { u16 u[8]; bf16x8 v; } o;
  o.u[0] = f2b(lo.x); o.u[1] = f2b(lo.y); o.u[2] = f2b(lo.z); o.u[3] = f2b(lo.w);
  o.u[4] = f2b(hi.x); o.u[5] = f2b(hi.y); o.u[6] = f2b(hi.z); o.u[7] = f2b(hi.w);
  return o.v;
}

// =============================================================================
// Fused init: blocks 0..511 cast Wk,Wo -> bf16; block 512 compacts usage;
// blocks 513..528 zero lsum[16384].  Block-uniform branching.  (R8-verified.)
// =============================================================================
__global__ void k_init(const float* __restrict__ wk, const float* __restrict__ wo,
                       u16* __restrict__ owk, u16* __restrict__ owo,
                       const int* __restrict__ usage, int* __restrict__ idx,
                       int* __restrict__ meta, float* __restrict__ lsum) {
  __shared__ int cnt[256];
  const int blk = blockIdx.x;
  const int t = threadIdx.x;
  if (blk < 512) {                                  // weight casts
    int i = blk * 256 + t;
    const float* src = (i < 65536) ? wk : wo;
    u16* dst = (i < 65536) ? owk : owo;
    int j = i & 65535;
    float4 v = ((const float4*)src)[j];
    ushort4 o;
    o.x = f2b(v.x); o.y = f2b(v.y); o.z = f2b(v.z); o.w = f2b(v.w);
    ((ushort4*)dst)[j] = o;
  } else if (blk == 512) {                          // compaction scan
    int base = t * 16;
    int c = 0;
    #pragma unroll
    for (int i = 0; i < 16; ++i) c += (usage[base + i] > 0) ? 1 : 0;
    cnt[t] = c;
    __syncthreads();
    for (int d = 1; d < 256; d <<= 1) {             // inclusive Hillis-Steele
      int v = (t >= d) ? cnt[t - d] : 0;
      __syncthreads();
      cnt[t] += v;
      __syncthreads();
    }
    int pos = cnt[t] - c;                           // exclusive prefix
    for (int i = 0; i < 16; ++i)
      if (usage[base + i] > 0) idx[pos++] = base + i;
    if (t == 0) {
      int total = cnt[255];
      int keff = ((total + 127) >> 7) << 7;         // 128-granular padding
      meta[0] = total; meta[1] = keff; meta[2] = keff >> 5; meta[3] = keff >> 7;
    }
  } else {                                          // zero lsum (16 blocks)
    int i = (blk - 513) * 256 + t;                  // 16*256 float4 = 16384 f
    float4 zf = {0.f, 0.f, 0.f, 0.f};
    ((float4*)lsum)[i] = zf;
  }
}

// =============================================================================
// MID mega-kernel: three INDEPENDENT jobs (all depend only on k_init) in one
// launch so they run concurrently instead of serializing on the stream:
//   blocks [0,256)   : QPROJ — R8-verified big-tile (BM=128 k, B from hidden
//                      fp32, 2-deep named-group pipeline, 1 barrier/K-step)
//   blocks [256,320) : MW — R6-verified 128x128 core (values gather + cast
//                      fused into B staging); threads >=256 idle but execute
//                      the SAME block-uniform loop/barrier sequence
//   blocks [320,832) : gather keys (L2-normalize + compact), 8 rows/block
// Shared memory: one 96 KB pool aliased per branch (QPROJ needs all of it).
// =============================================================================
__global__ __launch_bounds__(512, 2)
void k_mid(const u16* __restrict__ wkb, const float* __restrict__ hidden,
           u16* __restrict__ qb, const float* __restrict__ bk,
           float* __restrict__ qss,
           const u16* __restrict__ wob, const float* __restrict__ mvals,
           const int* __restrict__ idx, const int* __restrict__ meta,
           u16* __restrict__ MWt,
           const float* __restrict__ mkeys, u16* __restrict__ mkn) {
  __shared__ u16 smem[49152];                       // 96 KB pool
  const int blk = blockIdx.x;
  const int tid = threadIdx.x;
  const int lane = tid & 63;

  if (blk < 256) {
    // ------------------------- QPROJ (exact R8 core) -------------------------
    constexpr int NLA  = 2;
    constexpr int NLB  = 4;
    constexpr int ASUB = 128 * 32;                  // 4096 u16
    constexpr int BSUB = 256 * 32;                  // 8192 u16
    // Ah[cur] = smem + cur*8192 ; Bh[cur] = smem + 16384 + cur*16384
    u16* AhB = smem;
    u16* BhB = smem + 16384;

    const int wave = tid >> 6;
    const int wave_m = wave >> 2, wave_n = wave & 3;
    const int wm0 = wave_m * 64;
    const int wn0 = wave_n * 64;
    const int fr  = lane & 15, g = lane >> 4;
    const int fbase = g * 128 + fr * 8;

    int id = blk;
    int xcd = id & 7, s = id >> 3;
    const int r0 = (xcd * 8 + (s >> 2)) << 8;
    const int m0 = (s & 3) << 7;
    const int kiters = 512 >> 6;

    const char* Ac = (const char*)wkb;
    uint32_t aB[NLA], bB[NLB];
    #pragma unroll
    for (int s2 = 0; s2 < NLA; ++s2) {
      int u  = tid;
      int row = ((u >> 6) << 4) + (u & 15);
      int kch = (u >> 4) & 3;
      aB[s2] = (uint32_t)(((size_t)(m0 + row) * 512u
                           + (size_t)(s2 * 32 + kch * 8)) * 2u);
    }
    #pragma unroll
    for (int s2 = 0; s2 < NLB; ++s2) {
      int ks = s2 >> 1;
      int u  = tid + (s2 & 1) * 512;
      int row = ((u >> 6) << 4) + (u & 15);
      int kch = (u >> 4) & 3;
      bB[s2] = (uint32_t)(((size_t)(r0 + row) * 512u
                           + (size_t)(ks * 32 + kch * 8)) * 4u);
    }

    f32x4 acc[4][4];
    const f32x4 z = {0.0f, 0.0f, 0.0f, 0.0f};
    #pragma unroll
    for (int i = 0; i < 4; ++i)
      #pragma unroll
      for (int j = 0; j < 4; ++j) acc[i][j] = z;

    auto gloadA = [&](bf16x8 (&ra)[NLA], int it1) {
      const uint32_t kb = (uint32_t)(it1 << 7);
      #pragma unroll
      for (int s2 = 0; s2 < NLA; ++s2) ra[s2] = *(const bf16x8*)(Ac + aB[s2] + kb);
    };
    auto gloadBf = [&](float4 (&lo)[NLB], float4 (&hi)[NLB], int it1) {
      const uint32_t kb = (uint32_t)(it1 << 8);
      #pragma unroll
      for (int s2 = 0; s2 < NLB; ++s2) {
        lo[s2] = *(const float4*)((const char*)hidden + bB[s2] + kb);
        hi[s2] = *(const float4*)((const char*)hidden + bB[s2] + kb + 16);
      }
    };
    auto commitA = [&](int cur, bf16x8 (&ra)[NLA]) {
      #pragma unroll
      for (int s2 = 0; s2 < NLA; ++s2)
        *(bf16x8*)&AhB[cur * 8192 + s2 * ASUB + tid * 8] = ra[s2];
    };
    auto commitBf = [&](int cur, float4 (&lo)[NLB], float4 (&hi)[NLB]) {
      #pragma unroll
      for (int s2 = 0; s2 < NLB; ++s2)
        *(bf16x8*)&BhB[cur * 16384 + (s2 >> 1) * BSUB + (tid + (s2 & 1) * 512) * 8] =
            cvt8(lo[s2], hi[s2]);
    };
    auto compute = [&](int cur) {
      bf16x8 af[4], bfv[4];
      #pragma unroll
      for (int i = 0; i < 4; ++i)
        af[i] = *(const bf16x8*)&AhB[cur * 8192 + ((wm0 >> 4) + i) * 512 + fbase];
      #pragma unroll
      for (int j = 0; j < 4; ++j)
        bfv[j] = *(const bf16x8*)&BhB[cur * 16384 + ((wn0 >> 4) + j) * 512 + fbase];
      #pragma unroll
      for (int i = 0; i < 4; ++i)
        #pragma unroll
        for (int j = 0; j < 4; ++j)
          acc[i][j] = __builtin_amdgcn_mfma_f32_16x16x32_bf16(af[i], bfv[j], acc[i][j], 0, 0, 0);
      #pragma unroll
      for (int i = 0; i < 4; ++i)
        af[i] = *(const bf16x8*)&AhB[cur * 8192 + ASUB + ((wm0 >> 4) + i) * 512 + fbase];
      #pragma unroll
      for (int j = 0; j < 4; ++j)
        bfv[j] = *(const bf16x8*)&BhB[cur * 16384 + BSUB + ((wn0 >> 4) + j) * 512 + fbase];
      #pragma unroll
      for (int i = 0; i < 4; ++i)
        #pragma unroll
        for (int j = 0; j < 4; ++j)
          acc[i][j] = __builtin_amdgcn_mfma_f32_16x16x32_bf16(af[i], bfv[j], acc[i][j], 0, 0, 0);
    };

    bf16x8 a0[NLA], a1[NLA];
    float4 b0lo[NLB], b0hi[NLB], b1lo[NLB], b1hi[NLB];
    gloadA(a0, 0); gloadBf(b0lo, b0hi, 0);
    gloadA(a1, 1); gloadBf(b1lo, b1hi, 1);
    for (int it = 0; it < kiters; it += 2) {
      commitA(0, a0); commitBf(0, b0lo, b0hi);
      if (it + 2 < kiters) { gloadA(a0, it + 2); gloadBf(b0lo, b0hi, it + 2); }
      __syncthreads();
      compute(0);
      commitA(1, a1); commitBf(1, b1lo, b1hi);
      if (it + 3 < kiters) { gloadA(a1, it + 3); gloadBf(b1lo, b1hi, it + 3); }
      __syncthreads();
      compute(1);
    }

    float sj[4] = {0.f, 0.f, 0.f, 0.f};
    #pragma unroll
    for (int i = 0; i < 4; ++i) {
      const int kb = m0 + wm0 + i * 16 + g * 4;
      const float4 bkv = *(const float4*)(bk + kb);
      #pragma unroll
      for (int j = 0; j < 4; ++j) {
        const size_t rr = (size_t)(r0 + wn0 + j * 16 + fr);
        float v0 = acc[i][j][0] + bkv.x;
        float v1 = acc[i][j][1] + bkv.y;
        float v2 = acc[i][j][2] + bkv.z;
        float v3 = acc[i][j][3] + bkv.w;
        ushort4 st; st.x = f2b(v0); st.y = f2b(v1); st.z = f2b(v2); st.w = f2b(v3);
        *(ushort4*)(qb + rr * H_DIM + kb) = st;
        sj[j] += v0 * v0 + v1 * v1 + v2 * v2 + v3 * v3;
      }
    }
    const int slot = (m0 + wm0) >> 6;
    #pragma unroll
    for (int j = 0; j < 4; ++j) {
      float s2 = sj[j];
      s2 += __shfl_xor(s2, 16, 64);
      s2 += __shfl_xor(s2, 32, 64);
      if (lane < 16)
        qss[(size_t)(r0 + wn0 + j * 16 + lane) * 8 + slot] = s2;
    }

  } else if (blk < 320) {
    // ----------------- MW (R6 core); threads >=256 idle-but-sync -------------
    const int mb_blk = (blk - 256) & 15;            // m block
    const int hb_blk = (blk - 256) >> 4;            // h block
    if (mb_blk >= (meta[1] >> 7)) return;           // block-uniform, pre-barrier
    const bool act = (tid < 256);                   // wave-uniform (waves 0-3)

    // Ah[cur] = smem + cur*4096 ; Bh[cur] = smem + 8192 + cur*4096
    u16* AhB = smem;
    u16* BhB = smem + 8192;

    const int t256 = tid & 255;
    const int wave = t256 >> 6;
    const int wr = (wave >> 1) * 64;
    const int wc = (wave & 1) * 64;
    const int count = meta[0];
    const int row0 = hb_blk << 7;
    const int col0 = mb_blk << 7;
    const int kiters = 512 >> 5;

    const int srow   = lane & 15;
    const int schunk = lane >> 4;
    const int lds_off = schunk * 128 + srow * 8;
    const int fr = lane & 15;
    const int fbase = (lane >> 4) * 128 + fr * 8;
    const int g = lane >> 4;

    const char* Ac = (const char*)wob;

    uint32_t aB[2], bB[2];
    bool bval[2] = {false, false};
    if (act) {
      #pragma unroll
      for (int s2 = 0; s2 < 2; ++s2) {
        aB[s2] = (uint32_t)(((size_t)(row0 + (wave + s2 * 4) * 16 + srow) * 512u
                             + (size_t)(schunk * 8)) * 2u);
        int mrow = col0 + (wave + s2 * 4) * 16 + srow;
        bval[s2] = (mrow < count);
        int src = bval[s2] ? idx[mrow] : 0;
        bB[s2] = (uint32_t)(((size_t)src * 512u + (size_t)(schunk * 8)) * 4u);
      }
    }

    f32x4 acc[4][4];
    const f32x4 z = {0.0f, 0.0f, 0.0f, 0.0f};
    #pragma unroll
    for (int i = 0; i < 4; ++i)
      #pragma unroll
      for (int j = 0; j < 4; ++j) acc[i][j] = z;

    bf16x8 rA[2];
    float4 rBlo[2], rBhi[2];
    auto gload = [&](int k0) {
      const uint32_t kb  = (uint32_t)(k0 << 1);
      const uint32_t kbf = (uint32_t)(k0 << 2);
      #pragma unroll
      for (int s2 = 0; s2 < 2; ++s2) rA[s2] = *(const bf16x8*)(Ac + aB[s2] + kb);
      #pragma unroll
      for (int s2 = 0; s2 < 2; ++s2) {
        rBlo[s2] = *(const float4*)((const char*)mvals + bB[s2] + kbf);
        rBhi[s2] = *(const float4*)((const char*)mvals + bB[s2] + kbf + 16);
      }
    };

    const float4 zf = {0.f, 0.f, 0.f, 0.f};
    if (act) gload(0);
    for (int it = 0; it < kiters; ++it) {
      const int cur = it & 1;
      if (act) {
        #pragma unroll
        for (int s2 = 0; s2 < 2; ++s2)
          *(bf16x8*)&AhB[cur * 4096 + (wave + s2 * 4) * 512 + lds_off] = rA[s2];
        #pragma unroll
        for (int s2 = 0; s2 < 2; ++s2)
          *(bf16x8*)&BhB[cur * 4096 + (wave + s2 * 4) * 512 + lds_off] =
              bval[s2] ? cvt8(rBlo[s2], rBhi[s2]) : cvt8(zf, zf);
        if (it + 1 < kiters) gload((it + 1) << 5);
      }
      __syncthreads();                              // all 512 threads
      if (act) {
        bf16x8 af[4], bfv[4];
        #pragma unroll
        for (int i = 0; i < 4; ++i)
          af[i] = *(const bf16x8*)&AhB[cur * 4096 + ((wr >> 4) + i) * 512 + fbase];
        #pragma unroll
        for (int j = 0; j < 4; ++j)
          bfv[j] = *(const bf16x8*)&BhB[cur * 4096 + ((wc >> 4) + j) * 512 + fbase];
        #pragma unroll
        for (int i = 0; i < 4; ++i)
          #pragma unroll
          for (int j = 0; j < 4; ++j)
            acc[i][j] = __builtin_amdgcn_mfma_f32_16x16x32_bf16(af[i], bfv[j], acc[i][j], 0, 0, 0);
      }
    }

    if (act) {
      #pragma unroll
      for (int i = 0; i < 4; ++i) {
        #pragma unroll
        for (int r = 0; r < 4; ++r) {
          int grow = row0 + wr + i * 16 + g * 4 + r;
          #pragma unroll
          for (int j = 0; j < 4; ++j) {
            int gcol = col0 + wc + j * 16 + fr;
            MWt[(size_t)grow * (size_t)M_DIM + gcol] = f2b(acc[i][j][r]);
          }
        }
      }
    }

  } else {
    // --------------------- gather keys: 8 rows per block ---------------------
    int j = (blk - 320) * 8 + (tid >> 6);
    int count = meta[0];
    ushort4* kp = (ushort4*)(mkn + (size_t)j * H_DIM);
    if (j >= count) {                               // wave-uniform
      ushort4 zz = {0, 0, 0, 0};
      kp[lane] = zz; kp[lane + 64] = zz;
      return;
    }
    int src = idx[j];
    const float4* rp = (const float4*)(mkeys + (size_t)src * H_DIM);
    float4 a = rp[lane];
    float4 b = rp[lane + 64];
    float ss = a.x*a.x + a.y*a.y + a.z*a.z + a.w*a.w
             + b.x*b.x + b.y*b.y + b.z*b.z + b.w*b.w;
    #pragma unroll
    for (int d = 1; d < 64; d <<= 1) ss += __shfl_xor(ss, d, 64);
    float s = rsqrtf(ss + 1e-6f);
    ushort4 oa, ob;
    oa.x = f2b(a.x*s); oa.y = f2b(a.y*s); oa.z = f2b(a.z*s); oa.w = f2b(a.w*s);
    ob.x = f2b(b.x*s); ob.y = f2b(b.y*s); ob.z = f2b(b.z*s); ob.w = f2b(b.w*s);
    kp[lane]      = oa;
    kp[lane + 64] = ob;
  }
}

// =============================================================================
// Big-tile BT GEMM — EXACT R8 CORE (verified 245.5 µs config), P and OUT only.
// 512 thr = 8 waves (2Mx4N), BK=64, reg-staged single-barrier double buffer;
// loads issued right after ds_write commit, BEFORE the barrier.  OUT uses the
// 2-deep named-group pipeline; P (MF=8) stays 1-deep.
//   EPI2_P  : row-sum partials -> atomicAdd(lsum[r]); folded rsqrt(qss)
//   EPI2_OUT: scl = 1/lsum[r] inline
// =============================================================================
#define EPI2_P     0
#define EPI2_OUT   1

template<int EPI>
__global__ __launch_bounds__(512, 2)
void k_gemm2(const u16* __restrict__ A, const u16* __restrict__ B,
             const int* __restrict__ meta,
             float* __restrict__ outf, u16* __restrict__ outh,
             const float* __restrict__ bias,
             float* __restrict__ aux,
             const float* __restrict__ rowscale) {
  constexpr int BM   = (EPI == EPI2_P) ? 256 : 128; // A rows per tile
  constexpr int MF   = BM / 32;                     // m-frags per wave: 8 / 4
  constexpr int NF   = 4;                           // r-frags per wave
  constexpr int APS  = BM / 128;                    // A loads per sub-tile: 2 / 1
  constexpr int NLA  = BM / 64;                     // A loads per thread: 4 / 2
  constexpr int NLB  = 4;                           // B loads per thread
  constexpr int ASUB = BM * 32;                     // u16 per A sub-tile
  constexpr int BSUB = 256 * 32;                    // u16 per B sub-tile

  __shared__ u16 Ah[2][BM * 64];
  __shared__ u16 Bh[2][256 * 64];

  const int tid  = threadIdx.x;
  const int wave = tid >> 6, lane = tid & 63;
  const int wave_m = wave >> 2, wave_n = wave & 3;
  const int wm0 = wave_m * (BM >> 1);               // wave m-offset
  const int wn0 = wave_n * 64;                      // wave r-offset
  const int fr  = lane & 15, g = lane >> 4;
  const int fbase = g * 128 + fr * 8;               // fragment LDS offset (u16)

  int m0, r0, kel;
  if (EPI == EPI2_P) {
    // grid (16,64): XCD-swizzled; all 16 m-blocks of 8 r-blocks per XCD
    int id = blockIdx.x + (blockIdx.y << 4);
    int xcd = id & 7, s = id >> 3;
    r0 = (xcd * 8 + (s >> 4)) << 8;
    m0 = (s & 15) << 8;
    if (m0 >= meta[1]) return;                      // inactive m-block
    kel = 512;
  } else {
    // grid (4,64): XCD-swizzled; the 4 h-blocks of 8 r-blocks per XCD
    int id = blockIdx.x + (blockIdx.y << 2);
    int xcd = id & 7, s = id >> 3;
    r0 = (xcd * 8 + (s >> 2)) << 8;
    m0 = (s & 3) << 7;                              // h0
    kel = meta[1];
  }
  const int kiters = kel >> 6;                      // always even (kel 128-granular)
  if (kiters <= 0) return;
  const int kstr = (EPI == EPI2_OUT) ? M_DIM : 512; // row stride (elements)

  const char* Ac = (const char*)A;
  const char* Bc = (const char*)B;
  uint32_t aB[NLA], bB[NLB];
  #pragma unroll
  for (int s2 = 0; s2 < NLA; ++s2) {
    int ks = s2 / APS;
    int u  = tid + (s2 % APS) * 512;
    int row = ((u >> 6) << 4) + (u & 15);
    int kch = (u >> 4) & 3;
    aB[s2] = (uint32_t)(((size_t)(m0 + row) * (size_t)kstr
                         + (size_t)(ks * 32 + kch * 8)) * 2u);
  }
  #pragma unroll
  for (int s2 = 0; s2 < NLB; ++s2) {
    int ks = s2 >> 1;
    int u  = tid + (s2 & 1) * 512;
    int row = ((u >> 6) << 4) + (u & 15);
    int kch = (u >> 4) & 3;
    bB[s2] = (uint32_t)(((size_t)(r0 + row) * (size_t)kstr
                         + (size_t)(ks * 32 + kch * 8)) * 2u);
  }

  f32x4 acc[MF][NF];
  const f32x4 z = {0.0f, 0.0f, 0.0f, 0.0f};
  #pragma unroll
  for (int i = 0; i < MF; ++i)
    #pragma unroll
    for (int j = 0; j < NF; ++j) acc[i][j] = z;

  auto gloadA = [&](bf16x8 (&ra)[NLA], int it1) {
    const uint32_t kb = (uint32_t)(it1 << 7);       // 64 k-cols * 2B
    #pragma unroll
    for (int s2 = 0; s2 < NLA; ++s2) ra[s2] = *(const bf16x8*)(Ac + aB[s2] + kb);
  };
  auto gloadBh = [&](bf16x8 (&rb)[NLB], int it1) {
    const uint32_t kb = (uint32_t)(it1 << 7);
    #pragma unroll
    for (int s2 = 0; s2 < NLB; ++s2) rb[s2] = *(const bf16x8*)(Bc + bB[s2] + kb);
  };
  auto commitA = [&](int cur, bf16x8 (&ra)[NLA]) {
    #pragma unroll
    for (int s2 = 0; s2 < NLA; ++s2)
      *(bf16x8*)&Ah[cur][(s2 / APS) * ASUB + (tid + (s2 % APS) * 512) * 8] = ra[s2];
  };
  auto commitBh = [&](int cur, bf16x8 (&rb)[NLB]) {
    #pragma unroll
    for (int s2 = 0; s2 < NLB; ++s2)
      *(bf16x8*)&Bh[cur][(s2 >> 1) * BSUB + (tid + (s2 & 1) * 512) * 8] = rb[s2];
  };
  auto compute = [&](int cur) {
    bf16x8 af[MF], bfv[NF];
    #pragma unroll
    for (int i = 0; i < MF; ++i)
      af[i] = *(const bf16x8*)&Ah[cur][((wm0 >> 4) + i) * 512 + fbase];
    #pragma unroll
    for (int j = 0; j < NF; ++j)
      bfv[j] = *(const bf16x8*)&Bh[cur][((wn0 >> 4) + j) * 512 + fbase];
    #pragma unroll
    for (int i = 0; i < MF; ++i)
      #pragma unroll
      for (int j = 0; j < NF; ++j)
        acc[i][j] = __builtin_amdgcn_mfma_f32_16x16x32_bf16(af[i], bfv[j], acc[i][j], 0, 0, 0);
    #pragma unroll
    for (int i = 0; i < MF; ++i)
      af[i] = *(const bf16x8*)&Ah[cur][ASUB + ((wm0 >> 4) + i) * 512 + fbase];
    #pragma unroll
    for (int j = 0; j < NF; ++j)
      bfv[j] = *(const bf16x8*)&Bh[cur][BSUB + ((wn0 >> 4) + j) * 512 + fbase];
    #pragma unroll
    for (int i = 0; i < MF; ++i)
      #pragma unroll
      for (int j = 0; j < NF; ++j)
        acc[i][j] = __builtin_amdgcn_mfma_f32_16x16x32_bf16(af[i], bfv[j], acc[i][j], 0, 0, 0);
  };

  if constexpr (EPI == EPI2_P) {
    // 1-deep pipeline: commit; refill; barrier; compute.
    bf16x8 rA[NLA], rB[NLB];
    gloadA(rA, 0); gloadBh(rB, 0);
    for (int it = 0; it < kiters; ++it) {
      const int cur = it & 1;
      commitA(cur, rA); commitBh(cur, rB);
      if (it + 1 < kiters) { gloadA(rA, it + 1); gloadBh(rB, it + 1); }
      __syncthreads();                              // lgkmcnt only
      compute(cur);
    }
  } else {
    // 2-deep pipeline: named groups, 2-iter unrolled.
    bf16x8 a0[NLA], b0[NLB], a1[NLA], b1[NLB];
    gloadA(a0, 0); gloadBh(b0, 0);
    if (kiters > 1) { gloadA(a1, 1); gloadBh(b1, 1); }
    for (int it = 0; it < kiters; it += 2) {
      commitA(0, a0); commitBh(0, b0);
      if (it + 2 < kiters) { gloadA(a0, it + 2); gloadBh(b0, it + 2); }
      __syncthreads();
      compute(0);
      commitA(1, a1); commitBh(1, b1);
      if (it + 3 < kiters) { gloadA(a1, it + 3); gloadBh(b1, it + 3); }
      __syncthreads();
      compute(1);
    }
  }

  // Epilogues. C/D layout per 16x16 tile: col = lane&15, row = (lane>>4)*4 + reg.
  if (EPI == EPI2_P) {
    const int count = meta[0];
    float rq10[NF];
    #pragma unroll
    for (int j = 0; j < NF; ++j) {
      const size_t rr = (size_t)(r0 + wn0 + j * 16 + fr);
      float ssum = 0.0f;                            // folded k_rsq
      #pragma unroll
      for (int i = 0; i < 8; ++i) ssum += rowscale[rr * 8 + i];
      rq10[j] = rsqrtf(ssum + 1e-6f) * 10.0f;
    }
    float sj[NF] = {0.f, 0.f, 0.f, 0.f};
    #pragma unroll
    for (int i = 0; i < MF; ++i) {
      const int mb = m0 + wm0 + i * 16 + g * 4;     // 4 consecutive m
      #pragma unroll
      for (int j = 0; j < NF; ++j) {
        const size_t rr = (size_t)(r0 + wn0 + j * 16 + fr);
        float p0 = (mb + 0 < count) ? __expf(acc[i][j][0] * rq10[j]) : 0.0f;
        float p1 = (mb + 1 < count) ? __expf(acc[i][j][1] * rq10[j]) : 0.0f;
        float p2 = (mb + 2 < count) ? __expf(acc[i][j][2] * rq10[j]) : 0.0f;
        float p3 = (mb + 3 < count) ? __expf(acc[i][j][3] * rq10[j]) : 0.0f;
        ushort4 st; st.x = f2b(p0); st.y = f2b(p1); st.z = f2b(p2); st.w = f2b(p3);
        *(ushort4*)(outh + rr * M_DIM + mb) = st;   // packed 8B, [r][m]
        sj[j] += (p0 + p1) + (p2 + p3);
      }
    }
    // per-wave row-sum partial -> atomic accumulate
    #pragma unroll
    for (int j = 0; j < NF; ++j) {
      float s = sj[j];
      s += __shfl_xor(s, 16, 64);
      s += __shfl_xor(s, 32, 64);
      if (lane < 16)
        atomicAdd(&aux[(size_t)(r0 + wn0 + j * 16 + lane)], s);
    }
  } else { // EPI2_OUT
    float scl[NF];
    #pragma unroll
    for (int j = 0; j < NF; ++j)
      scl[j] = 1.0f / rowscale[r0 + wn0 + j * 16 + fr];   // linv inline
    #pragma unroll
    for (int i = 0; i < MF; ++i) {
      const int hb = m0 + wm0 + i * 16 + g * 4;     // 4 consecutive h
      const float4 bv = *(const float4*)(bias + hb);
      #pragma unroll
      for (int j = 0; j < NF; ++j) {
        const size_t rr = (size_t)(r0 + wn0 + j * 16 + fr);
        float4 o;
        o.x = acc[i][j][0] * scl[j] + bv.x;
        o.y = acc[i][j][1] * scl[j] + bv.y;
        o.z = acc[i][j][2] * scl[j] + bv.z;
        o.w = acc[i][j][3] * scl[j] + bv.w;
        *(float4*)(outf + rr * H_DIM + hb) = o;     // coalesced 16B store
      }
    }
  }
}

extern "C" void kernel_launch(void* const* d_in, const int* in_sizes, int n_in,
                              void* d_out, int out_size, void* d_ws, size_t ws_size,
                              hipStream_t stream) {
  const float* hidden = (const float*)d_in[0];   // [16384, 512]
  const float* mkeys  = (const float*)d_in[1];   // [4096, 512]
  const float* mvals  = (const float*)d_in[2];   // [4096, 512]
  const float* Wk     = (const float*)d_in[3];   // [512, 512]
  const float* bk     = (const float*)d_in[4];   // [512]
  const float* Wo     = (const float*)d_in[5];   // [512, 512]
  const float* bo     = (const float*)d_in[6];   // [512]
  const int*   usage  = (const int*)d_in[7];     // [4096]
  (void)in_sizes; (void)n_in; (void)out_size; (void)ws_size;

  char* ws = (char*)d_ws;
  int*   idx   = (int*)(ws + 0);            //      16,384  compacted->orig map
  int*   meta  = (int*)(ws + 16384);        //          16  {count, K_eff, K/32, K/128}
  float* lsum  = (float*)(ws + 1048576);    //      65,536  softmax row sums [16384]
  float* qss   = (float*)(ws + 5242880);    //     524,288  q sumsq partials [16384,8]
  u16*   wkb   = (u16*)(ws + 16777216);     //     524,288  Wk bf16
  u16*   wob   = (u16*)(ws + 17301504);     //     524,288  Wo bf16
  u16*   mkn   = (u16*)(ws + 17825792);     //   4,194,304  compacted normalized keys bf16
  u16*   qb    = (u16*)(ws + 26214400);     //  16,777,216  q bf16 [r][k]
  u16*   MWt   = (u16*)(ws + 42991616);     //   4,194,304  (mvals@Wo^T)^T bf16 [512,4096]
  u16*   P     = (u16*)(ws + 47185920);     // 134,217,728  exp-scores bf16 [16384,4096]

  // 1) fused init: weight casts + compaction + lsum zeroing
  k_init<<<529, 256, 0, stream>>>(Wk, Wo, wkb, wob, usage, idx, meta, lsum);

  // 2) fused mid: QPROJ (blocks 0-255) | MW (256-319) | gather keys (320-831)
  k_mid<<<832, 512, 0, stream>>>(wkb, hidden, qb, bk, qss,
                                 wob, mvals, idx, meta, MWt,
                                 mkeys, mkn);

  // 3) P[r,m] = exp(10 * (qb @ mkn^T) * rsqrt(|q_r|^2+eps)); lsum atomics
  k_gemm2<EPI2_P><<<dim3(16, 64), 512, 0, stream>>>(mkn, qb, meta,
      nullptr, P, nullptr, lsum, qss);

  // 4) out[r,h] = (P @ MWt^T) / lsum[r] + bo
  k_gemm2<EPI2_OUT><<<dim3(4, 64), 512, 0, stream>>>(MWt, P, meta,
      (float*)d_out, nullptr, bo, nullptr, lsum);
}